// Round 14
// baseline (767.992 us; speedup 1.0000x reference)
//
#include <hip/hip_runtime.h>
#include <hip/hip_bf16.h>

#define HLAT 181
#define WLON 360
#define HW (HLAT * WLON)
#define HPAD 188
#define WPAD 368
#define PCH ((size_t)HPAD * WPAD * 16)        // ushorts per h1 chunk-plane
#define W2P 372
#define PLANE2 ((size_t)HPAD * W2P * 64)      // ushorts per h2 part-plane
#define ZROW ((size_t)384 * 64)               // ushorts per (bi,h) zbuf row

typedef __attribute__((ext_vector_type(4)))  short short4v;
typedef __attribute__((ext_vector_type(8)))  short short8v;
typedef __attribute__((ext_vector_type(4)))  float f32x4;
typedef __attribute__((ext_vector_type(16))) float f32x16;

static __device__ __forceinline__ ushort bf16_hi_bits(float f) {
  union { float f; unsigned u; } c; c.f = f;
  unsigned u = c.u;
  unsigned rounded = u + 0x7FFF + ((u >> 16) & 1);  // RNE
  return (ushort)(rounded >> 16);
}
static __device__ __forceinline__ float bf16_to_f(ushort b) {
  union { unsigned u; float f; } c; c.u = ((unsigned)b) << 16;
  return c.f;
}

// ---------------- kernel 0: weight prep ----------------
// w2f entry idx = (tap*8+ch)*4 + m*2 + p ; lane l, j: part p of
//   w2[oc=m*32+(l&31)][ci=ch*16+(l>>5)*8+j][tap]     (32x32x16 A order)
// w1f entry idx = (m*2+kc)*2 + p ; lane l, j: part p of W1[oc=m*32+(l&31)][k]
//   k = kc*16+(l>>5)*8+j; W1[o][k<27]=w1, W1[o][27]=b1, else 0.
// w3f entry idx = (tap*2+kc)*2 + p ; lane l, j: part p of
//   W3[oc=l&15][ci=kc*32+(l>>4)*8+j][tap], oc>=3 -> 0   (16x16x32 A order)
__global__ __launch_bounds__(256) void k_tw(const float* __restrict__ w2,
                                            const float* __restrict__ w3,
                                            const float* __restrict__ w1,
                                            const float* __restrict__ b1,
                                            ushort* __restrict__ w2f,
                                            ushort* __restrict__ w1f,
                                            ushort* __restrict__ w3f) {
  int idx = blockIdx.x * 256 + threadIdx.x;
  if (idx < 51200) {
    int l   = idx & 63;
    int p   = (idx >> 6) & 1;
    int m   = (idx >> 7) & 1;
    int ch  = (idx >> 8) & 7;
    int tap = idx >> 11;
    int oc  = m * 32 + (l & 31);
    int ci0 = ch * 16 + (l >> 5) * 8;
#pragma unroll
    for (int j = 0; j < 8; ++j) {
      float f = w2[(oc * 128 + ci0 + j) * 25 + tap];
      ushort hi = bf16_hi_bits(f);
      w2f[(size_t)idx * 8 + j] = (p == 0) ? hi : bf16_hi_bits(f - bf16_to_f(hi));
    }
  }
  if (idx < 1024) {
    int l = idx & 63;
    int e = idx >> 6;
    int p  = e & 1;
    int kc = (e >> 1) & 1;
    int m  = e >> 2;
    int oc = m * 32 + (l & 31);
    int k0 = kc * 16 + (l >> 5) * 8;
#pragma unroll
    for (int j = 0; j < 8; ++j) {
      int k = k0 + j;
      float f = (k < 27) ? w1[oc * 27 + k] : (k == 27 ? b1[oc] : 0.f);
      ushort hi = bf16_hi_bits(f);
      w1f[(size_t)idx * 8 + j] = (p == 0) ? hi : bf16_hi_bits(f - bf16_to_f(hi));
    }
  }
  if (idx < 6400) {
    int l   = idx & 63;
    int p   = (idx >> 6) & 1;
    int kc  = (idx >> 7) & 1;
    int tap = idx >> 8;               // 0..24
    int oc  = l & 15;
    int ci0 = kc * 32 + (l >> 4) * 8;
#pragma unroll
    for (int j = 0; j < 8; ++j) {
      float f = (oc < 3) ? w3[(oc * 64 + ci0 + j) * 25 + tap] : 0.f;
      ushort hi = bf16_hi_bits(f);
      w3f[(size_t)idx * 8 + j] = (p == 0) ? hi : bf16_hi_bits(f - bf16_to_f(hi));
    }
  }
}

// ---------------- zero pad ring of h1 chunk-planes (4024 px each) ---------
__global__ __launch_bounds__(256) void k_zring(ushort* __restrict__ h1s) {
  const int i = blockIdx.x * 256 + threadIdx.x;
  if (i >= 4024) return;
  int row, col;
  if (i < 736)       { row = i / 368;              col = i % 368; }
  else if (i < 2576) { int p = i - 736;  row = 183 + p / 368; col = p % 368; }
  else if (i < 2938) { int p = i - 2576; row = 2 + p % 181;   col = p / 181; }
  else               { int p = i - 2938; row = 2 + p % 181;   col = 362 + p / 181; }
  short8v z = {0, 0, 0, 0, 0, 0, 0, 0};
  short8v* d = (short8v*)(h1s + (size_t)blockIdx.y * PCH + ((size_t)row * 368 + col) * 16);
  d[0] = z; d[1] = z;
}

// ---------------- zero pad ring of h2 part-planes (4776 px each) ----------
__global__ __launch_bounds__(256) void k_zring2(ushort* __restrict__ h2p) {
  const int i = blockIdx.x * 256 + threadIdx.x;
  if (i >= 4776) return;
  int row, col;
  if (i < 744)       { row = i / W2P;             col = i % W2P; }
  else if (i < 2604) { int p = i - 744;  row = 183 + p / W2P; col = p % W2P; }
  else               { int p = i - 2604; row = 2 + p % 181;
                       int cI = p / 181; col = (cI < 2) ? cI : 360 + cI; }
  short8v z = {0, 0, 0, 0, 0, 0, 0, 0};
  short8v* d = (short8v*)(h2p + (size_t)blockIdx.y * PLANE2 + ((size_t)row * W2P + col) * 64);
#pragma unroll
  for (int k = 0; k < 8; ++k) d[k] = z;
}

// ---------------- kernel 1a: disco z (pure VALU, 1 px/thread) -------------
// zbuf row layout per (bi,h): [px 0..383][part][kc][16k] bf16 bits.
// px 360..383 zero-filled. Bias lane k=27 -> 1.0.
__global__ __launch_bounds__(384, 2) void k_z(const float* __restrict__ x,
    const float* __restrict__ psi, const float* __restrict__ quad,
    ushort* __restrict__ zbuf, int b0) {
  const int h = blockIdx.x;
  const int bi = blockIdx.y;
  const int b = b0 + bi;
  const int tid = threadIdx.x;
  ushort* dst = zbuf + (size_t)(bi * HLAT + h) * ZROW + (size_t)tid * 64;
  if (tid >= 360) {
    short8v zz = {0, 0, 0, 0, 0, 0, 0, 0};
    short8v* d8 = (short8v*)dst;
#pragma unroll
    for (int k = 0; k < 8; ++k) d8[k] = zz;
    return;
  }
  float z[28];
#pragma unroll
  for (int q = 0; q < 28; ++q) z[q] = 0.f;
#pragma unroll 1
  for (int i = 0; i < 5; ++i) {
    int hi = h + i - 2;
    hi = hi < 0 ? 0 : (hi >= HLAT ? HLAT - 1 : hi);
    const float qv = quad[hi];
    float pv[45];
#pragma unroll
    for (int kk = 0; kk < 9; ++kk)
#pragma unroll
      for (int j = 0; j < 5; ++j)
        pv[kk * 5 + j] = psi[((size_t)(kk * HLAT + h)) * 25 + i * 5 + j];
#pragma unroll
    for (int c = 0; c < 3; ++c) {
      const float* row = x + ((size_t)(b * 3 + c) * HLAT + hi) * WLON;
      float v[5];
#pragma unroll
      for (int j = 0; j < 5; ++j) {
        int wj = tid + j - 2;
        wj = wj < 0 ? wj + WLON : (wj >= WLON ? wj - WLON : wj);
        v[j] = row[wj] * qv;
      }
#pragma unroll
      for (int kk = 0; kk < 9; ++kk) {
        float a = 0.f;
#pragma unroll
        for (int j = 0; j < 5; ++j) a += pv[kk * 5 + j] * v[j];
        z[c * 9 + kk] += a;
      }
    }
  }
  z[27] = 1.0f;   // bias column
  ushort hiv[32], lov[32];
#pragma unroll
  for (int q = 0; q < 28; ++q) {
    const ushort hb = bf16_hi_bits(z[q]);
    hiv[q] = hb;
    lov[q] = bf16_hi_bits(z[q] - bf16_to_f(hb));
  }
#pragma unroll
  for (int q = 28; q < 32; ++q) { hiv[q] = 0; lov[q] = 0; }
#pragma unroll
  for (int part = 0; part < 2; ++part)
#pragma unroll
    for (int kc = 0; kc < 2; ++kc)
#pragma unroll
      for (int half = 0; half < 2; ++half) {
        union { ushort u[8]; short8v v8; } t8;
#pragma unroll
        for (int j = 0; j < 8; ++j)
          t8.u[j] = (part == 0 ? hiv : lov)[kc * 16 + half * 8 + j];
        *(short8v*)&dst[part * 32 + kc * 16 + half * 8] = t8.v8;
      }
}

// ---------------- kernel 1b: w1 matvec via MFMA (B from global) -----------
// grid (HLAT, bc) block 256 (4 waves x 3 px-frags). No LDS, no barrier.
__global__ __launch_bounds__(256, 2) void k_mv(const ushort* __restrict__ zbuf,
    const ushort* __restrict__ w1f, ushort* __restrict__ h1s) {
  const int h = blockIdx.x;
  const int bi = blockIdx.y;
  const int tid = threadIdx.x;
  const int wv = tid >> 6;
  const int l = tid & 63;
  const int l31 = l & 31;
  const int q = l >> 5;
  const short8v* wf1 = (const short8v*)w1f;
  short8v A[4][2][2];   // [m][kc][part]
#pragma unroll
  for (int m = 0; m < 4; ++m)
#pragma unroll
    for (int kc = 0; kc < 2; ++kc)
#pragma unroll
      for (int p = 0; p < 2; ++p)
        A[m][kc][p] = wf1[(size_t)(((m * 2 + kc) * 2 + p) * 64 + l)];

  ushort* base = h1s + (size_t)bi * 16 * PCH;
  const ushort* zrow = zbuf + (size_t)(bi * HLAT + h) * ZROW;
#pragma unroll
  for (int nn = 0; nn < 3; ++nn) {
    const int n = wv * 3 + nn;
    const int px = n * 32 + l31;
    const ushort* zp = zrow + (size_t)px * 64 + q * 8;
    const short8v bh0 = *(const short8v*)(zp + 0);    // part0 kc0
    const short8v bh1 = *(const short8v*)(zp + 16);   // part0 kc1
    const short8v bl0 = *(const short8v*)(zp + 32);   // part1 kc0
    const short8v bl1 = *(const short8v*)(zp + 48);   // part1 kc1
    const bool ok = px < 360;
    const size_t pixoff = ((size_t)(h + 2) * WPAD + (px + 2)) * 16;
#pragma unroll
    for (int m = 0; m < 4; ++m) {
      f32x16 acc;
#pragma unroll
      for (int e = 0; e < 16; ++e) acc[e] = 0.f;
      acc = __builtin_amdgcn_mfma_f32_32x32x16_bf16(A[m][0][0], bh0, acc, 0, 0, 0);
      acc = __builtin_amdgcn_mfma_f32_32x32x16_bf16(A[m][0][1], bh0, acc, 0, 0, 0);
      acc = __builtin_amdgcn_mfma_f32_32x32x16_bf16(A[m][0][0], bl0, acc, 0, 0, 0);
      acc = __builtin_amdgcn_mfma_f32_32x32x16_bf16(A[m][1][0], bh1, acc, 0, 0, 0);
      acc = __builtin_amdgcn_mfma_f32_32x32x16_bf16(A[m][1][1], bh1, acc, 0, 0, 0);
      acc = __builtin_amdgcn_mfma_f32_32x32x16_bf16(A[m][1][0], bl1, acc, 0, 0, 0);
      if (ok) {
#pragma unroll
        for (int r = 0; r < 4; ++r) {
          const int rb = 8 * r + 4 * q;
          const int ch = m * 2 + (rb >> 4);
          const int ci0 = rb & 15;
          short4v h4, l4;
#pragma unroll
          for (int j = 0; j < 4; ++j) {
            const float v = fmaxf(acc[r * 4 + j], 0.f);
            const ushort hb = bf16_hi_bits(v);
            h4[j] = (short)hb;
            l4[j] = (short)bf16_hi_bits(v - bf16_to_f(hb));
          }
          *(short4v*)(base + (size_t)ch * PCH + pixoff + ci0) = h4;
          *(short4v*)(base + (size_t)(8 + ch) * PCH + pixoff + ci0) = l4;
        }
      }
    }
  }
}

// ---------------- kernel 2: conv 128->64 via bf16x3 MFMA ------------------
// R9 core; epilogue writes h2 as bf16 hi/lo padded planes [y+2][x+2][64ci].
__global__ __launch_bounds__(256, 2) void k_conv2(const ushort* __restrict__ h1s,
    const ushort* __restrict__ w2f, const float* __restrict__ b2,
    ushort* __restrict__ h2p) {
  __shared__ ushort act[2][2][12][40][16];  // 61440 B
  const int x0 = blockIdx.x * 32;
  const int y0 = blockIdx.y * 8;
  const int bi = blockIdx.z;
  const int tid = threadIdx.x;
  const int wv = tid >> 6;
  const int m  = wv >> 1;
  const int wr = wv & 1;
  const int l = tid & 63;
  const int l31 = l & 31;
  const int q8 = (l >> 5) * 8;

  f32x16 acc[4];
#pragma unroll
  for (int r = 0; r < 4; ++r)
#pragma unroll
    for (int e = 0; e < 16; ++e) acc[r][e] = 0.f;

  const short8v* wf = (const short8v*)w2f;
  const ushort* pbase = h1s + (size_t)bi * 16 * PCH;

  auto stage = [&](int buf, int ch) {
#pragma unroll
    for (int s = 0; s < 12; ++s) {
      const int k = wv * 12 + s;
      const int part = k / 24;
      const int rem = k - part * 24;
      const int t = rem >> 1;
      const int slot = rem & 1;
      const ushort* pl = pbase + (size_t)(part * 8 + ch) * PCH;
      if (slot == 0) {
        const ushort* g = pl + ((size_t)(y0 + t) * WPAD + (x0 + (l >> 1))) * 16 + (l & 1) * 8;
        __builtin_amdgcn_global_load_lds(
            (const __attribute__((address_space(1))) unsigned int*)g,
            (__attribute__((address_space(3))) unsigned int*)&act[buf][part][t][0][0], 16, 0, 0);
      } else {
        const ushort* g = pl + ((size_t)(y0 + t) * WPAD + (x0 + 32 + (l >> 3))) * 16 + (l & 7) * 2;
        __builtin_amdgcn_global_load_lds(
            (const __attribute__((address_space(1))) unsigned int*)g,
            (__attribute__((address_space(3))) unsigned int*)&act[buf][part][t][32][0], 4, 0, 0);
      }
    }
  };

  stage(0, 0);
  asm volatile("s_waitcnt vmcnt(0)" ::: "memory");
  __syncthreads();

#pragma unroll 1
  for (int ch = 0; ch < 8; ++ch) {
    const int cur = ch & 1;
    if (ch < 7) stage(cur ^ 1, ch + 1);
#pragma unroll 1
    for (int dj = 0; dj < 5; ++dj) {
      short8v aw[5][2];
#pragma unroll
      for (int di = 0; di < 5; ++di) {
        const size_t e0 = (size_t)(((di * 5 + dj) * 8 + ch) * 4 + m * 2) * 64 + l;
        aw[di][0] = wf[e0];
        aw[di][1] = wf[e0 + 64];
      }
      __builtin_amdgcn_s_setprio(1);
#pragma unroll
      for (int rr = 0; rr < 8; ++rr) {
        const int t = wr * 4 + rr;
        const int c = l31 + dj;
        const short8v bh = *(const short8v*)&act[cur][0][t][c][q8];
        const short8v bl = *(const short8v*)&act[cur][1][t][c][q8];
#pragma unroll
        for (int di = 0; di < 5; ++di) {
          const int r = rr - di;
          if (r < 0 || r > 3) continue;
          acc[r] = __builtin_amdgcn_mfma_f32_32x32x16_bf16(aw[di][0], bh, acc[r], 0, 0, 0);
          acc[r] = __builtin_amdgcn_mfma_f32_32x32x16_bf16(aw[di][1], bh, acc[r], 0, 0, 0);
          acc[r] = __builtin_amdgcn_mfma_f32_32x32x16_bf16(aw[di][0], bl, acc[r], 0, 0, 0);
        }
      }
      __builtin_amdgcn_s_setprio(0);
    }
    asm volatile("s_waitcnt vmcnt(0)" ::: "memory");
    __syncthreads();
  }

  // oc of acc element e: (e&3) + 8*(e>>2) + 4*(l>>5) + 32*m.
  const int xg = x0 + l31;
  ushort* hp = h2p + (size_t)bi * 2 * PLANE2;
  if (xg < WLON) {
#pragma unroll
    for (int r = 0; r < 4; ++r) {
      const int y = y0 + wr * 4 + r;
      if (y >= HLAT) continue;
      const size_t po = ((size_t)(y + 2) * W2P + (xg + 2)) * 64;
#pragma unroll
      for (int run = 0; run < 4; ++run) {
        const int oc0 = m * 32 + 8 * run + (q8 >> 1);
        short4v h4, l4;
#pragma unroll
        for (int j = 0; j < 4; ++j) {
          const float v = fmaxf(acc[r][run * 4 + j] + b2[oc0 + j], 0.f);
          const ushort hb = bf16_hi_bits(v);
          h4[j] = (short)hb;
          l4[j] = (short)bf16_hi_bits(v - bf16_to_f(hb));
        }
        *(short4v*)(hp + po + oc0) = h4;
        *(short4v*)(hp + PLANE2 + po + oc0) = l4;
      }
    }
  }
}

// ---------------- kernel 3: conv 64->3 via bf16x3 MFMA (16x16x32) ---------
__global__ __launch_bounds__(256, 2) void k_conv3(const ushort* __restrict__ h2p,
    const ushort* __restrict__ w3f, const float* __restrict__ b3,
    float* __restrict__ out, int b0) {
  __shared__ ushort act[2][12][20][72];   // 69120 B
  const int x0 = blockIdx.x * 16;
  const int y0 = blockIdx.y * 8;
  const int bi = blockIdx.z;
  const int tid = threadIdx.x;
  const int wv = tid >> 6;
  const int l = tid & 63;

  {
    const ushort* pb = h2p + (size_t)bi * 2 * PLANE2;
    float4 v[6][3];
#pragma unroll
    for (int pr = 0; pr < 6; ++pr) {
      const int pair = wv * 6 + pr;
      const int part = pair / 12;
      const int row = pair % 12;
      const ushort* src = pb + (size_t)part * PLANE2 +
                          ((size_t)(y0 + row) * W2P + x0) * 64;
      v[pr][0] = *(const float4*)((const char*)src + l * 16);
      v[pr][1] = *(const float4*)((const char*)src + 1024 + l * 16);
      if (l < 32) v[pr][2] = *(const float4*)((const char*)src + 2048 + l * 16);
    }
#pragma unroll
    for (int pr = 0; pr < 6; ++pr) {
      const int pair = wv * 6 + pr;
      const int part = pair / 12;
      const int row = pair % 12;
#pragma unroll
      for (int k2 = 0; k2 < 3; ++k2) {
        if (k2 == 2 && l >= 32) continue;
        const int B = k2 * 1024 + l * 16;
        const int col = B >> 7;
        const int ci = (B & 127) >> 1;
        *(short8v*)&act[part][row][col][ci] = *(short8v*)&v[pr][k2];
      }
    }
  }
  __syncthreads();

  f32x4 acc[2];
#pragma unroll
  for (int r = 0; r < 2; ++r)
#pragma unroll
    for (int e = 0; e < 4; ++e) acc[r][e] = 0.f;

  const short8v* wf3 = (const short8v*)w3f;
  const int c16 = l & 15;
  const int koff0 = ((l >> 4) & 3) * 8;

#pragma unroll 1
  for (int kc = 0; kc < 2; ++kc) {
#pragma unroll 1
    for (int dj = 0; dj < 5; ++dj) {
      short8v A[5][2];
#pragma unroll
      for (int di = 0; di < 5; ++di) {
        const size_t e0 = (size_t)(((di * 5 + dj) * 2 + kc) * 2) * 64 + l;
        A[di][0] = wf3[e0];
        A[di][1] = wf3[e0 + 64];
      }
      const int c = c16 + dj;
      const int koff = kc * 32 + koff0;
      __builtin_amdgcn_s_setprio(1);
#pragma unroll
      for (int tt = 0; tt < 6; ++tt) {
        const int t = wv * 2 + tt;
        const short8v bh = *(const short8v*)&act[0][t][c][koff];
        const short8v bl = *(const short8v*)&act[1][t][c][koff];
#pragma unroll
        for (int di = 0; di < 5; ++di) {
          const int r = tt - di;
          if (r < 0 || r > 1) continue;
          acc[r] = __builtin_amdgcn_mfma_f32_16x16x32_bf16(A[di][0], bh, acc[r], 0, 0, 0);
          acc[r] = __builtin_amdgcn_mfma_f32_16x16x32_bf16(A[di][1], bh, acc[r], 0, 0, 0);
          acc[r] = __builtin_amdgcn_mfma_f32_16x16x32_bf16(A[di][0], bl, acc[r], 0, 0, 0);
        }
      }
      __builtin_amdgcn_s_setprio(0);
    }
  }

  const int px = x0 + c16;
  const int b = b0 + bi;
  if ((l >> 4) == 0 && px < WLON) {
    const float bb[3] = {b3[0], b3[1], b3[2]};
#pragma unroll
    for (int r = 0; r < 2; ++r) {
      const int y = y0 + wv * 2 + r;
      if (y >= HLAT) continue;
#pragma unroll
      for (int j = 0; j < 3; ++j)
        out[((size_t)(b * 3 + j) * HLAT + y) * WLON + px] = acc[r][j] + bb[j];
    }
  }
}

extern "C" void kernel_launch(void* const* d_in, const int* in_sizes, int n_in,
                              void* d_out, int out_size, void* d_ws, size_t ws_size,
                              hipStream_t stream) {
  const float* x    = (const float*)d_in[0];
  const float* psi  = (const float*)d_in[1];
  const float* quad = (const float*)d_in[2];
  const float* w1   = (const float*)d_in[3];
  const float* b1   = (const float*)d_in[4];
  const float* w2   = (const float*)d_in[5];
  const float* b2   = (const float*)d_in[6];
  const float* w3   = (const float*)d_in[7];
  const float* b3   = (const float*)d_in[8];
  float* out = (float*)d_out;
  float* ws  = (float*)d_ws;

  ushort* w2f = (ushort*)ws;              // 409600 ushorts = 204800 fl
  ushort* w1f = (ushort*)(ws + 204800);   // 8192 ushorts   = 4096 fl
  ushort* w3f = (ushort*)(ws + 208896);   // 51200 ushorts  = 25600 fl
  const size_t HEAD = 234496;             // floats

  size_t wsf = ws_size / 4;
  const size_t h1s_f = PCH * 8;           // floats: 16 chunk-planes per batch
  const size_t h2p_f = PLANE2;            // floats: 2 part-planes per batch
  const size_t per_b = h1s_f + h2p_f;
  int bc = 8;
  while (bc > 1 && HEAD + (size_t)bc * per_b > wsf) bc >>= 1;

  ushort* h1s = (ushort*)(ws + HEAD);
  ushort* h2p = (ushort*)(ws + HEAD + (size_t)bc * h1s_f);
  // zbuf aliases the h2p region: zbuf lifetime [k_z, k_mv] precedes h2p
  // lifetime [k_conv2, k_conv3] within each loop iteration (stream-ordered).
  // Size: bc*181*384*64 ush = bc*4.45M <= bc*2*PLANE2 = bc*8.95M ush. OK.
  ushort* zbuf = h2p;

  k_tw<<<dim3(200), dim3(256), 0, stream>>>(w2, w3, w1, b1, w2f, w1f, w3f);
  k_zring<<<dim3(16, bc * 16), dim3(256), 0, stream>>>(h1s);

  for (int b0 = 0; b0 < 8; b0 += bc) {
    int cur = 8 - b0 < bc ? 8 - b0 : bc;
    k_z<<<dim3(HLAT, cur), dim3(384), 0, stream>>>(x, psi, quad, zbuf, b0);
    k_mv<<<dim3(HLAT, cur), dim3(256), 0, stream>>>(zbuf, w1f, h1s);
    // zero h2p pad rings AFTER zbuf (aliased) is consumed, BEFORE conv2.
    k_zring2<<<dim3(19, cur * 2), dim3(256), 0, stream>>>(h2p);
    k_conv2<<<dim3(12, 23, cur), dim3(256), 0, stream>>>(h1s, w2f, b2, h2p);
    k_conv3<<<dim3(23, 23, cur), dim3(256), 0, stream>>>(h2p, w3f, b3, out, b0);
  }
}

// Round 15
// 756.892 us; speedup vs baseline: 1.0147x; 1.0147x over previous
//
#include <hip/hip_runtime.h>
#include <hip/hip_bf16.h>

#define HLAT 181
#define WLON 360
#define HW (HLAT * WLON)
#define HPAD 188
#define WPAD 368
#define PCH ((size_t)HPAD * WPAD * 16)        // ushorts per h1 chunk-plane
#define W2P 372
#define PLANE2 ((size_t)HPAD * W2P * 64)      // ushorts per h2 part-plane
#define ZROW ((size_t)12 * 4 * 32 * 16)       // ushorts per (bi,h) zbuf row = 24576

typedef __attribute__((ext_vector_type(4)))  short short4v;
typedef __attribute__((ext_vector_type(8)))  short short8v;
typedef __attribute__((ext_vector_type(4)))  float f32x4;
typedef __attribute__((ext_vector_type(16))) float f32x16;

static __device__ __forceinline__ ushort bf16_hi_bits(float f) {
  union { float f; unsigned u; } c; c.f = f;
  unsigned u = c.u;
  unsigned rounded = u + 0x7FFF + ((u >> 16) & 1);  // RNE
  return (ushort)(rounded >> 16);
}
static __device__ __forceinline__ float bf16_to_f(ushort b) {
  union { unsigned u; float f; } c; c.u = ((unsigned)b) << 16;
  return c.f;
}

// ---------------- kernel 0: weight prep ----------------
__global__ __launch_bounds__(256) void k_tw(const float* __restrict__ w2,
                                            const float* __restrict__ w3,
                                            const float* __restrict__ w1,
                                            const float* __restrict__ b1,
                                            ushort* __restrict__ w2f,
                                            ushort* __restrict__ w1f,
                                            ushort* __restrict__ w3f) {
  int idx = blockIdx.x * 256 + threadIdx.x;
  if (idx < 51200) {
    int l   = idx & 63;
    int p   = (idx >> 6) & 1;
    int m   = (idx >> 7) & 1;
    int ch  = (idx >> 8) & 7;
    int tap = idx >> 11;
    int oc  = m * 32 + (l & 31);
    int ci0 = ch * 16 + (l >> 5) * 8;
#pragma unroll
    for (int j = 0; j < 8; ++j) {
      float f = w2[(oc * 128 + ci0 + j) * 25 + tap];
      ushort hi = bf16_hi_bits(f);
      w2f[(size_t)idx * 8 + j] = (p == 0) ? hi : bf16_hi_bits(f - bf16_to_f(hi));
    }
  }
  if (idx < 1024) {
    int l = idx & 63;
    int e = idx >> 6;
    int p  = e & 1;
    int kc = (e >> 1) & 1;
    int m  = e >> 2;
    int oc = m * 32 + (l & 31);
    int k0 = kc * 16 + (l >> 5) * 8;
#pragma unroll
    for (int j = 0; j < 8; ++j) {
      int k = k0 + j;
      float f = (k < 27) ? w1[oc * 27 + k] : (k == 27 ? b1[oc] : 0.f);
      ushort hi = bf16_hi_bits(f);
      w1f[(size_t)idx * 8 + j] = (p == 0) ? hi : bf16_hi_bits(f - bf16_to_f(hi));
    }
  }
  if (idx < 6400) {
    int l   = idx & 63;
    int p   = (idx >> 6) & 1;
    int kc  = (idx >> 7) & 1;
    int tap = idx >> 8;               // 0..24
    int oc  = l & 15;
    int ci0 = kc * 32 + (l >> 4) * 8;
#pragma unroll
    for (int j = 0; j < 8; ++j) {
      float f = (oc < 3) ? w3[(oc * 64 + ci0 + j) * 25 + tap] : 0.f;
      ushort hi = bf16_hi_bits(f);
      w3f[(size_t)idx * 8 + j] = (p == 0) ? hi : bf16_hi_bits(f - bf16_to_f(hi));
    }
  }
}

// ---------------- zero pad ring of h1 chunk-planes (4024 px each) ---------
__global__ __launch_bounds__(256) void k_zring(ushort* __restrict__ h1s) {
  const int i = blockIdx.x * 256 + threadIdx.x;
  if (i >= 4024) return;
  int row, col;
  if (i < 736)       { row = i / 368;              col = i % 368; }
  else if (i < 2576) { int p = i - 736;  row = 183 + p / 368; col = p % 368; }
  else if (i < 2938) { int p = i - 2576; row = 2 + p % 181;   col = p / 181; }
  else               { int p = i - 2938; row = 2 + p % 181;   col = 362 + p / 181; }
  short8v z = {0, 0, 0, 0, 0, 0, 0, 0};
  short8v* d = (short8v*)(h1s + (size_t)blockIdx.y * PCH + ((size_t)row * 368 + col) * 16);
  d[0] = z; d[1] = z;
}

// ---------------- zero pad ring of h2 part-planes (4776 px each) ----------
__global__ __launch_bounds__(256) void k_zring2(ushort* __restrict__ h2p) {
  const int i = blockIdx.x * 256 + threadIdx.x;
  if (i >= 4776) return;
  int row, col;
  if (i < 744)       { row = i / W2P;             col = i % W2P; }
  else if (i < 2604) { int p = i - 744;  row = 183 + p / W2P; col = p % W2P; }
  else               { int p = i - 2604; row = 2 + p % 181;
                       int cI = p / 181; col = (cI < 2) ? cI : 360 + cI; }
  short8v z = {0, 0, 0, 0, 0, 0, 0, 0};
  short8v* d = (short8v*)(h2p + (size_t)blockIdx.y * PLANE2 + ((size_t)row * W2P + col) * 64);
#pragma unroll
  for (int k = 0; k < 8; ++k) d[k] = z;
}

// ---------------- kernel 1a: disco z (pure VALU, 1 px/thread) -------------
// zbuf row per (bi,h): [n 12][pk 4][px 32][16k] bf16 bits, pk = part*2+kc.
// Dense stores: 32B/thread contiguous per pk-plane. px>=360 slots zeroed.
__global__ __launch_bounds__(384, 2) void k_z(const float* __restrict__ x,
    const float* __restrict__ psi, const float* __restrict__ quad,
    ushort* __restrict__ zbuf, int b0) {
  const int h = blockIdx.x;
  const int bi = blockIdx.y;
  const int b = b0 + bi;
  const int tid = threadIdx.x;
  float z[28];
#pragma unroll
  for (int q = 0; q < 28; ++q) z[q] = 0.f;
  if (tid < 360) {
#pragma unroll 1
    for (int i = 0; i < 5; ++i) {
      int hi = h + i - 2;
      hi = hi < 0 ? 0 : (hi >= HLAT ? HLAT - 1 : hi);
      const float qv = quad[hi];
      float pv[45];
#pragma unroll
      for (int kk = 0; kk < 9; ++kk)
#pragma unroll
        for (int j = 0; j < 5; ++j)
          pv[kk * 5 + j] = psi[((size_t)(kk * HLAT + h)) * 25 + i * 5 + j];
#pragma unroll
      for (int c = 0; c < 3; ++c) {
        const float* row = x + ((size_t)(b * 3 + c) * HLAT + hi) * WLON;
        float v[5];
#pragma unroll
        for (int j = 0; j < 5; ++j) {
          int wj = tid + j - 2;
          wj = wj < 0 ? wj + WLON : (wj >= WLON ? wj - WLON : wj);
          v[j] = row[wj] * qv;
        }
#pragma unroll
        for (int kk = 0; kk < 9; ++kk) {
          float a = 0.f;
#pragma unroll
          for (int j = 0; j < 5; ++j) a += pv[kk * 5 + j] * v[j];
          z[c * 9 + kk] += a;
        }
      }
    }
    z[27] = 1.0f;   // bias column
  }
  ushort hiv[32], lov[32];
#pragma unroll
  for (int q = 0; q < 28; ++q) {
    const ushort hb = bf16_hi_bits(z[q]);
    hiv[q] = hb;
    lov[q] = bf16_hi_bits(z[q] - bf16_to_f(hb));
  }
#pragma unroll
  for (int q = 28; q < 32; ++q) { hiv[q] = 0; lov[q] = 0; }

  ushort* tb = zbuf + (size_t)(bi * HLAT + h) * ZROW +
               (size_t)(tid >> 5) * 2048 + (size_t)(tid & 31) * 16;
#pragma unroll
  for (int pk = 0; pk < 4; ++pk) {
    const ushort* src = (pk < 2 ? hiv : lov) + (pk & 1) * 16;
    union { ushort u[8]; short8v v8; } a0, a1;
#pragma unroll
    for (int j = 0; j < 8; ++j) { a0.u[j] = src[j]; a1.u[j] = src[8 + j]; }
    *(short8v*)(tb + (size_t)pk * 512 + 0) = a0.v8;
    *(short8v*)(tb + (size_t)pk * 512 + 8) = a1.v8;
  }
}

// ---------------- kernel 1b: w1 matvec via MFMA, dense stores -------------
// grid (HLAT, bc) block 256 (4 waves x 3 px-frags). B from zbuf (dense 1KB
// reads). Epilogue: per-wave LDS transpose st[wv] (wave-private, no barrier)
// then 16 dense 1KB stores per frag into h1s chunk planes.
__global__ __launch_bounds__(256, 2) void k_mv(const ushort* __restrict__ zbuf,
    const ushort* __restrict__ w1f, ushort* __restrict__ h1s) {
  __shared__ ushort st[4][16][32][16];   // [wave][plane][px][ci16] = 64 KB
  const int h = blockIdx.x;
  const int bi = blockIdx.y;
  const int tid = threadIdx.x;
  const int wv = tid >> 6;
  const int l = tid & 63;
  const int l31 = l & 31;
  const int q = l >> 5;
  const short8v* wf1 = (const short8v*)w1f;
  short8v A[4][2][2];   // [m][kc][part]
#pragma unroll
  for (int m = 0; m < 4; ++m)
#pragma unroll
    for (int kc = 0; kc < 2; ++kc)
#pragma unroll
      for (int p = 0; p < 2; ++p)
        A[m][kc][p] = wf1[(size_t)(((m * 2 + kc) * 2 + p) * 64 + l)];

  ushort* base = h1s + (size_t)bi * 16 * PCH;
  const ushort* zrow = zbuf + (size_t)(bi * HLAT + h) * ZROW;
#pragma unroll
  for (int nn = 0; nn < 3; ++nn) {
    const int n = wv * 3 + nn;
    const ushort* zn = zrow + (size_t)n * 2048 + l31 * 16 + q * 8;
    const short8v bh0 = *(const short8v*)(zn + 0);     // pk0: part0 kc0
    const short8v bh1 = *(const short8v*)(zn + 512);   // pk1: part0 kc1
    const short8v bl0 = *(const short8v*)(zn + 1024);  // pk2: part1 kc0
    const short8v bl1 = *(const short8v*)(zn + 1536);  // pk3: part1 kc1
#pragma unroll
    for (int m = 0; m < 4; ++m) {
      f32x16 acc;
#pragma unroll
      for (int e = 0; e < 16; ++e) acc[e] = 0.f;
      acc = __builtin_amdgcn_mfma_f32_32x32x16_bf16(A[m][0][0], bh0, acc, 0, 0, 0);
      acc = __builtin_amdgcn_mfma_f32_32x32x16_bf16(A[m][0][1], bh0, acc, 0, 0, 0);
      acc = __builtin_amdgcn_mfma_f32_32x32x16_bf16(A[m][0][0], bl0, acc, 0, 0, 0);
      acc = __builtin_amdgcn_mfma_f32_32x32x16_bf16(A[m][1][0], bh1, acc, 0, 0, 0);
      acc = __builtin_amdgcn_mfma_f32_32x32x16_bf16(A[m][1][1], bh1, acc, 0, 0, 0);
      acc = __builtin_amdgcn_mfma_f32_32x32x16_bf16(A[m][1][0], bl1, acc, 0, 0, 0);
#pragma unroll
      for (int r = 0; r < 4; ++r) {
        const int rb = 8 * r + 4 * q;
        const int p2h = m * 2 + (rb >> 4);   // plane within part 0
        const int ci0 = rb & 15;
        short4v h4, l4;
#pragma unroll
        for (int j = 0; j < 4; ++j) {
          const float v = fmaxf(acc[r * 4 + j], 0.f);
          const ushort hb = bf16_hi_bits(v);
          h4[j] = (short)hb;
          l4[j] = (short)bf16_hi_bits(v - bf16_to_f(hb));
        }
        *(short4v*)&st[wv][p2h][l31][ci0] = h4;
        *(short4v*)&st[wv][8 + p2h][l31][ci0] = l4;
      }
    }
    // dense store: lane l covers px = n*32 + (l>>1), 16B half (l&1)
    const int pxr = n * 32 + (l >> 1);
    if (pxr < 360) {
      const size_t po = ((size_t)(h + 2) * WPAD + (pxr + 2)) * 16 + (l & 1) * 8;
#pragma unroll
      for (int p2 = 0; p2 < 16; ++p2) {
        const short8v v = *(const short8v*)&st[wv][p2][l >> 1][(l & 1) * 8];
        *(short8v*)(base + (size_t)p2 * PCH + po) = v;
      }
    }
  }
}

// ---------------- kernel 2: conv 128->64 via bf16x3 MFMA ------------------
// R9 core; epilogue writes h2 as bf16 hi/lo padded planes [y+2][x+2][64ci].
__global__ __launch_bounds__(256, 2) void k_conv2(const ushort* __restrict__ h1s,
    const ushort* __restrict__ w2f, const float* __restrict__ b2,
    ushort* __restrict__ h2p) {
  __shared__ ushort act[2][2][12][40][16];  // 61440 B
  const int x0 = blockIdx.x * 32;
  const int y0 = blockIdx.y * 8;
  const int bi = blockIdx.z;
  const int tid = threadIdx.x;
  const int wv = tid >> 6;
  const int m  = wv >> 1;
  const int wr = wv & 1;
  const int l = tid & 63;
  const int l31 = l & 31;
  const int q8 = (l >> 5) * 8;

  f32x16 acc[4];
#pragma unroll
  for (int r = 0; r < 4; ++r)
#pragma unroll
    for (int e = 0; e < 16; ++e) acc[r][e] = 0.f;

  const short8v* wf = (const short8v*)w2f;
  const ushort* pbase = h1s + (size_t)bi * 16 * PCH;

  auto stage = [&](int buf, int ch) {
#pragma unroll
    for (int s = 0; s < 12; ++s) {
      const int k = wv * 12 + s;
      const int part = k / 24;
      const int rem = k - part * 24;
      const int t = rem >> 1;
      const int slot = rem & 1;
      const ushort* pl = pbase + (size_t)(part * 8 + ch) * PCH;
      if (slot == 0) {
        const ushort* g = pl + ((size_t)(y0 + t) * WPAD + (x0 + (l >> 1))) * 16 + (l & 1) * 8;
        __builtin_amdgcn_global_load_lds(
            (const __attribute__((address_space(1))) unsigned int*)g,
            (__attribute__((address_space(3))) unsigned int*)&act[buf][part][t][0][0], 16, 0, 0);
      } else {
        const ushort* g = pl + ((size_t)(y0 + t) * WPAD + (x0 + 32 + (l >> 3))) * 16 + (l & 7) * 2;
        __builtin_amdgcn_global_load_lds(
            (const __attribute__((address_space(1))) unsigned int*)g,
            (__attribute__((address_space(3))) unsigned int*)&act[buf][part][t][32][0], 4, 0, 0);
      }
    }
  };

  stage(0, 0);
  asm volatile("s_waitcnt vmcnt(0)" ::: "memory");
  __syncthreads();

#pragma unroll 1
  for (int ch = 0; ch < 8; ++ch) {
    const int cur = ch & 1;
    if (ch < 7) stage(cur ^ 1, ch + 1);
#pragma unroll 1
    for (int dj = 0; dj < 5; ++dj) {
      short8v aw[5][2];
#pragma unroll
      for (int di = 0; di < 5; ++di) {
        const size_t e0 = (size_t)(((di * 5 + dj) * 8 + ch) * 4 + m * 2) * 64 + l;
        aw[di][0] = wf[e0];
        aw[di][1] = wf[e0 + 64];
      }
      __builtin_amdgcn_s_setprio(1);
#pragma unroll
      for (int rr = 0; rr < 8; ++rr) {
        const int t = wr * 4 + rr;
        const int c = l31 + dj;
        const short8v bh = *(const short8v*)&act[cur][0][t][c][q8];
        const short8v bl = *(const short8v*)&act[cur][1][t][c][q8];
#pragma unroll
        for (int di = 0; di < 5; ++di) {
          const int r = rr - di;
          if (r < 0 || r > 3) continue;
          acc[r] = __builtin_amdgcn_mfma_f32_32x32x16_bf16(aw[di][0], bh, acc[r], 0, 0, 0);
          acc[r] = __builtin_amdgcn_mfma_f32_32x32x16_bf16(aw[di][1], bh, acc[r], 0, 0, 0);
          acc[r] = __builtin_amdgcn_mfma_f32_32x32x16_bf16(aw[di][0], bl, acc[r], 0, 0, 0);
        }
      }
      __builtin_amdgcn_s_setprio(0);
    }
    asm volatile("s_waitcnt vmcnt(0)" ::: "memory");
    __syncthreads();
  }

  // oc of acc element e: (e&3) + 8*(e>>2) + 4*(l>>5) + 32*m.
  const int xg = x0 + l31;
  ushort* hp = h2p + (size_t)bi * 2 * PLANE2;
  if (xg < WLON) {
#pragma unroll
    for (int r = 0; r < 4; ++r) {
      const int y = y0 + wr * 4 + r;
      if (y >= HLAT) continue;
      const size_t po = ((size_t)(y + 2) * W2P + (xg + 2)) * 64;
#pragma unroll
      for (int run = 0; run < 4; ++run) {
        const int oc0 = m * 32 + 8 * run + (q8 >> 1);
        short4v h4, l4;
#pragma unroll
        for (int j = 0; j < 4; ++j) {
          const float v = fmaxf(acc[r][run * 4 + j] + b2[oc0 + j], 0.f);
          const ushort hb = bf16_hi_bits(v);
          h4[j] = (short)hb;
          l4[j] = (short)bf16_hi_bits(v - bf16_to_f(hb));
        }
        *(short4v*)(hp + po + oc0) = h4;
        *(short4v*)(hp + PLANE2 + po + oc0) = l4;
      }
    }
  }
}

// ---------------- kernel 3: conv 64->3 via bf16x3 MFMA (16x16x32) ---------
__global__ __launch_bounds__(256, 2) void k_conv3(const ushort* __restrict__ h2p,
    const ushort* __restrict__ w3f, const float* __restrict__ b3,
    float* __restrict__ out, int b0) {
  __shared__ ushort act[2][12][20][72];   // 69120 B
  const int x0 = blockIdx.x * 16;
  const int y0 = blockIdx.y * 8;
  const int bi = blockIdx.z;
  const int tid = threadIdx.x;
  const int wv = tid >> 6;
  const int l = tid & 63;

  {
    const ushort* pb = h2p + (size_t)bi * 2 * PLANE2;
    float4 v[6][3];
#pragma unroll
    for (int pr = 0; pr < 6; ++pr) {
      const int pair = wv * 6 + pr;
      const int part = pair / 12;
      const int row = pair % 12;
      const ushort* src = pb + (size_t)part * PLANE2 +
                          ((size_t)(y0 + row) * W2P + x0) * 64;
      v[pr][0] = *(const float4*)((const char*)src + l * 16);
      v[pr][1] = *(const float4*)((const char*)src + 1024 + l * 16);
      if (l < 32) v[pr][2] = *(const float4*)((const char*)src + 2048 + l * 16);
    }
#pragma unroll
    for (int pr = 0; pr < 6; ++pr) {
      const int pair = wv * 6 + pr;
      const int part = pair / 12;
      const int row = pair % 12;
#pragma unroll
      for (int k2 = 0; k2 < 3; ++k2) {
        if (k2 == 2 && l >= 32) continue;
        const int B = k2 * 1024 + l * 16;
        const int col = B >> 7;
        const int ci = (B & 127) >> 1;
        *(short8v*)&act[part][row][col][ci] = *(short8v*)&v[pr][k2];
      }
    }
  }
  __syncthreads();

  f32x4 acc[2];
#pragma unroll
  for (int r = 0; r < 2; ++r)
#pragma unroll
    for (int e = 0; e < 4; ++e) acc[r][e] = 0.f;

  const short8v* wf3 = (const short8v*)w3f;
  const int c16 = l & 15;
  const int koff0 = ((l >> 4) & 3) * 8;

#pragma unroll 1
  for (int kc = 0; kc < 2; ++kc) {
#pragma unroll 1
    for (int dj = 0; dj < 5; ++dj) {
      short8v A[5][2];
#pragma unroll
      for (int di = 0; di < 5; ++di) {
        const size_t e0 = (size_t)(((di * 5 + dj) * 2 + kc) * 2) * 64 + l;
        A[di][0] = wf3[e0];
        A[di][1] = wf3[e0 + 64];
      }
      const int c = c16 + dj;
      const int koff = kc * 32 + koff0;
      __builtin_amdgcn_s_setprio(1);
#pragma unroll
      for (int tt = 0; tt < 6; ++tt) {
        const int t = wv * 2 + tt;
        const short8v bh = *(const short8v*)&act[0][t][c][koff];
        const short8v bl = *(const short8v*)&act[1][t][c][koff];
#pragma unroll
        for (int di = 0; di < 5; ++di) {
          const int r = tt - di;
          if (r < 0 || r > 1) continue;
          acc[r] = __builtin_amdgcn_mfma_f32_16x16x32_bf16(A[di][0], bh, acc[r], 0, 0, 0);
          acc[r] = __builtin_amdgcn_mfma_f32_16x16x32_bf16(A[di][1], bh, acc[r], 0, 0, 0);
          acc[r] = __builtin_amdgcn_mfma_f32_16x16x32_bf16(A[di][0], bl, acc[r], 0, 0, 0);
        }
      }
      __builtin_amdgcn_s_setprio(0);
    }
  }

  const int px = x0 + c16;
  const int b = b0 + bi;
  if ((l >> 4) == 0 && px < WLON) {
    const float bb[3] = {b3[0], b3[1], b3[2]};
#pragma unroll
    for (int r = 0; r < 2; ++r) {
      const int y = y0 + wv * 2 + r;
      if (y >= HLAT) continue;
#pragma unroll
      for (int j = 0; j < 3; ++j)
        out[((size_t)(b * 3 + j) * HLAT + y) * WLON + px] = acc[r][j] + bb[j];
    }
  }
}

extern "C" void kernel_launch(void* const* d_in, const int* in_sizes, int n_in,
                              void* d_out, int out_size, void* d_ws, size_t ws_size,
                              hipStream_t stream) {
  const float* x    = (const float*)d_in[0];
  const float* psi  = (const float*)d_in[1];
  const float* quad = (const float*)d_in[2];
  const float* w1   = (const float*)d_in[3];
  const float* b1   = (const float*)d_in[4];
  const float* w2   = (const float*)d_in[5];
  const float* b2   = (const float*)d_in[6];
  const float* w3   = (const float*)d_in[7];
  const float* b3   = (const float*)d_in[8];
  float* out = (float*)d_out;
  float* ws  = (float*)d_ws;

  ushort* w2f = (ushort*)ws;              // 409600 ushorts = 204800 fl
  ushort* w1f = (ushort*)(ws + 204800);   // 8192 ushorts   = 4096 fl
  ushort* w3f = (ushort*)(ws + 208896);   // 51200 ushorts  = 25600 fl
  const size_t HEAD = 234496;             // floats

  size_t wsf = ws_size / 4;
  const size_t h1s_f = PCH * 8;           // floats: 16 chunk-planes per batch
  const size_t h2p_f = PLANE2;            // floats: 2 part-planes per batch
  const size_t per_b = h1s_f + h2p_f;
  int bc = 8;
  while (bc > 1 && HEAD + (size_t)bc * per_b > wsf) bc >>= 1;

  ushort* h1s = (ushort*)(ws + HEAD);
  ushort* h2p = (ushort*)(ws + HEAD + (size_t)bc * h1s_f);
  // zbuf aliases the h2p region: zbuf lifetime [k_z, k_mv] precedes h2p
  // lifetime [zring2, conv2, conv3] within each iteration (stream-ordered).
  // Size: bc*181*24576 ush <= bc*2*PLANE2 ush. OK.
  ushort* zbuf = h2p;

  k_tw<<<dim3(200), dim3(256), 0, stream>>>(w2, w3, w1, b1, w2f, w1f, w3f);
  k_zring<<<dim3(16, bc * 16), dim3(256), 0, stream>>>(h1s);

  for (int b0 = 0; b0 < 8; b0 += bc) {
    int cur = 8 - b0 < bc ? 8 - b0 : bc;
    k_z<<<dim3(HLAT, cur), dim3(384), 0, stream>>>(x, psi, quad, zbuf, b0);
    k_mv<<<dim3(HLAT, cur), dim3(256), 0, stream>>>(zbuf, w1f, h1s);
    // zero h2p pad rings AFTER zbuf (aliased) is consumed, BEFORE conv2.
    k_zring2<<<dim3(19, cur * 2), dim3(256), 0, stream>>>(h2p);
    k_conv2<<<dim3(12, 23, cur), dim3(256), 0, stream>>>(h1s, w2f, b2, h2p);
    k_conv3<<<dim3(23, 23, cur), dim3(256), 0, stream>>>(h2p, w3f, b3, out, b0);
  }
}